// Round 5
// baseline (268.353 us; speedup 1.0000x reference)
//
#include <hip/hip_runtime.h>
#include <hip/hip_bf16.h>
#include <stdint.h>

// Problem constants (fixed by reference)
#define TOKENS_C 8192
#define NIN_C    4096
#define NOUT_C   4096
#define GROUP_C  128
#define QZERO_C  8

typedef __bf16 bf16_t;
typedef __bf16  bf16x8 __attribute__((ext_vector_type(8)));
typedef float   f32x4  __attribute__((ext_vector_type(4)));
typedef int     i32x4  __attribute__((ext_vector_type(4)));

#define GAS __attribute__((address_space(1)))
#define LAS __attribute__((address_space(3)))

__device__ __forceinline__ void gload16(const void* g, void* l) {
  __builtin_amdgcn_global_load_lds((const GAS void*)g, (LAS void*)l, 16, 0, 0);
}

// ---------------- pass 1a: dequantize W (int32 codes 0..15) -> bf16 ----------
__global__ __launch_bounds__(256) void dequant_w_kernel(
    const int* __restrict__ qw, const float* __restrict__ sc,
    bf16_t* __restrict__ wb)
{
  const int t = blockIdx.x * 256 + threadIdx.x;
  const int64_t base = (int64_t)t * 8;
  const int o = (int)(base >> 12);
  const int i = (int)(base & 4095);
  const float s = sc[(o << 5) | (i >> 7)];
  i32x4 q0 = *(const i32x4*)(qw + base);
  i32x4 q1 = *(const i32x4*)(qw + base + 4);
  bf16x8 r;
  r[0] = (bf16_t)((float)(q0[0] - QZERO_C) * s);
  r[1] = (bf16_t)((float)(q0[1] - QZERO_C) * s);
  r[2] = (bf16_t)((float)(q0[2] - QZERO_C) * s);
  r[3] = (bf16_t)((float)(q0[3] - QZERO_C) * s);
  r[4] = (bf16_t)((float)(q1[0] - QZERO_C) * s);
  r[5] = (bf16_t)((float)(q1[1] - QZERO_C) * s);
  r[6] = (bf16_t)((float)(q1[2] - QZERO_C) * s);
  r[7] = (bf16_t)((float)(q1[3] - QZERO_C) * s);
  *(bf16x8*)(wb + base) = r;
}

// ---------------- pass 1b: convert x fp32 -> bf16 ----------------------------
__global__ __launch_bounds__(256) void cvt_x_kernel(
    const float* __restrict__ x, bf16_t* __restrict__ xb)
{
  const int t = blockIdx.x * 256 + threadIdx.x;
  const int64_t base = (int64_t)t * 8;
  f32x4 a = *(const f32x4*)(x + base);
  f32x4 b = *(const f32x4*)(x + base + 4);
  bf16x8 r;
  r[0] = (bf16_t)a[0]; r[1] = (bf16_t)a[1]; r[2] = (bf16_t)a[2]; r[3] = (bf16_t)a[3];
  r[4] = (bf16_t)b[0]; r[5] = (bf16_t)b[1]; r[6] = (bf16_t)b[2]; r[7] = (bf16_t)b[3];
  *(bf16x8*)(xb + base) = r;
}

// ---------------- pass 2: bf16 GEMM, C[M,N] = A[M,K] * B[N,K]^T --------------
// R4 8-phase schedule + one-phase-ahead LDS->reg fragment pipelining:
// aX/aY double-buffered A-frags; every phase issues NEXT phase's ds_reads
// before its MFMA cluster. STG/WAITV schedule identical to R4 (race-proven).
#define BM 256
#define BN 256
#define BK 64
#define NT (NIN_C / BK)   // 64 K-tiles -> 32 iterations of 2

__global__ __launch_bounds__(512, 2) void gemm_bt_kernel(
    const bf16_t* __restrict__ A,   // [M][K] bf16 (x)
    const bf16_t* __restrict__ B,   // [N][K] bf16 (W)
    float* __restrict__ C)          // [M][N] f32
{
  constexpr int K = NIN_C, N = NOUT_C;
  constexpr int K2 = K * 2;
  // A: dbuf d, half h at smem + d*32768 + h*16384
  // B: dbuf d, half h at smem + 65536 + d*32768 + h*16384
  __shared__ char smem[131072];

  const int tid  = threadIdx.x;
  const int lane = tid & 63;
  const int wid  = tid >> 6;       // 0..7
  const int wm   = wid >> 2;       // 0..1  -> 128 rows of C (== A half index)
  const int wn   = wid & 3;        // 0..3  -> 64 cols of C (B half = wn>>1)
  const int bm   = blockIdx.x;
  const int bn   = blockIdx.y;

  // ---- staging geometry: half = 128 rows x 128B; thread covers slots wid*2+l
  // (each 8 rows x 128B = 1KB); lane -> row slot*8+(lane>>3), granule lane&7.
  // LDS dest LINEAR; global source granule pre-swizzled with involution
  // g ^= (row&7) == (lane>>3). [R2/R4-verified: 0 bank conflicts]
  const int cswz = (((lane & 7) ^ (lane >> 3)) << 4);
  const char* Ag = (const char*)A;
  const char* Bg = (const char*)B;
  int64_t aso[2][2], bso[2][2];    // [half][l]
#pragma unroll
  for (int h = 0; h < 2; ++h)
#pragma unroll
    for (int l = 0; l < 2; ++l) {
      const int r = h * 128 + (wid * 2 + l) * 8 + (lane >> 3);
      aso[h][l] = (int64_t)(bm * BM + r) * K2 + cswz;
      bso[h][l] = (int64_t)(bn * BN + r) * K2 + cswz;
    }
  const int sdst = wid * 2048 + (lane << 4);  // + 1024 for l=1

#define STG_A(tt, h) { char* d_ = smem + (((tt) & 1) << 15) + ((h) << 14) + sdst; \
    gload16(Ag + aso[h][0] + (int64_t)(tt) * 128, d_);                            \
    gload16(Ag + aso[h][1] + (int64_t)(tt) * 128, d_ + 1024); }
#define STG_B(tt, h) { char* d_ = smem + 65536 + (((tt) & 1) << 15) + ((h) << 14) + sdst; \
    gload16(Bg + bso[h][0] + (int64_t)(tt) * 128, d_);                            \
    gload16(Bg + bso[h][1] + (int64_t)(tt) * 128, d_ + 1024); }

  // ---- fragment read geometry (16x16x32, BK=64 -> 2 k-subs) ----
  const int frow  = lane & 15;
  const int fcol0 = (((lane >> 4) ^ (lane & 7)) << 4);  // ks adds ^(ks<<6)

#define RD_B(dst, BB, ks)                                                      \
  _Pragma("unroll")                                                            \
  for (int j = 0; j < 4; ++j)                                                  \
    dst[j] = *(const bf16x8*)((BB) + ((wn & 1) * 64 + j * 16 + frow) * 128 +   \
                              (fcol0 ^ ((ks) << 6)));
#define RD_A(dst, AB, mh, ks)                                                  \
  _Pragma("unroll")                                                            \
  for (int i = 0; i < 4; ++i)                                                  \
    dst[i] = *(const bf16x8*)((AB) + ((mh) * 64 + i * 16 + frow) * 128 +       \
                              (fcol0 ^ ((ks) << 6)));
#define MM(mh, av, bv)                                                         \
  __builtin_amdgcn_s_setprio(1);                                               \
  _Pragma("unroll")                                                            \
  for (int i = 0; i < 4; ++i)                                                  \
    _Pragma("unroll")                                                          \
    for (int j = 0; j < 4; ++j)                                                \
      acc[(mh) * 4 + i][j] = __builtin_amdgcn_mfma_f32_16x16x32_bf16(          \
          av[i], bv[j], acc[(mh) * 4 + i][j], 0, 0, 0);                        \
  __builtin_amdgcn_s_setprio(0);
#define BAR __builtin_amdgcn_s_barrier()
#define WAITV(n) asm volatile("s_waitcnt vmcnt(" #n ")" ::: "memory")
#define SBAR0 __builtin_amdgcn_sched_barrier(0)

  const char* Ad0 = smem + wm * 16384;
  const char* Ad1 = smem + 32768 + wm * 16384;
  const char* Bd0 = smem + 65536 + (wn >> 1) * 16384;
  const char* Bd1 = smem + 98304 + (wn >> 1) * 16384;

  f32x4 acc[8][4] = {};
  bf16x8 aX[4], aY[4], b0[4], b1[4];

  // ---- prologue: stage tile0 A+B, tile1 B; force tile0 landed; preload
  // first phase's fragments (aX = A(t0,mh0,ks0), b0 = B(t0,ks0)). ----
  STG_A(0, 0); STG_A(0, 1);
  STG_B(0, 0); STG_B(0, 1);
  STG_B(1, 0); STG_B(1, 1);
  WAITV(4);                 // 12 issued; oldest 8 (tile0) done, B(1) in flight
  BAR; SBAR0;
  RD_A(aX, Ad0, 0, 0);
  RD_B(b0, Bd0, 0);

  // ---- main loop: iteration i computes tiles 2i (dbuf0), 2i+1 (dbuf1);
  // stages A(2i+1)@ph1/2, B(2i+2)@ph3/4, A(2i+2)@ph5/6, B(2i+3)@ph7/8.
  // Every phase issues the NEXT phase's fragment ds_reads before its MFMAs.
  for (int i = 0; i < NT / 2 - 1; ++i) {
    const int t0 = 2 * i;
    // ph1: consume aX=(0,0),b0 ; preload aY=(1,0), b1=ks1
    RD_A(aY, Ad0, 1, 0); RD_B(b1, Bd0, 1); STG_A(t0 + 1, 0); BAR; MM(0, aX, b0); BAR;
    // ph2: consume aY=(1,0),b0 ; preload aX=(0,1)
    RD_A(aX, Ad0, 0, 1); STG_A(t0 + 1, 1); BAR; MM(1, aY, b0); BAR;
    // ph3: consume aX=(0,1),b1 ; preload aY=(1,1)
    RD_A(aY, Ad0, 1, 1); STG_B(t0 + 2, 0); BAR; MM(0, aX, b1); BAR;
    // ph4: counted wait publishes tile t0+1 (dbuf1); then preload its frags
    STG_B(t0 + 2, 1); WAITV(4); BAR; SBAR0;
    RD_A(aX, Ad1, 0, 0); RD_B(b0, Bd1, 0); MM(1, aY, b1); BAR;
    // ph5: consume aX=A1(0,0),b0 ; preload aY=A1(1,0), b1=ks1
    RD_A(aY, Ad1, 1, 0); RD_B(b1, Bd1, 1); STG_A(t0 + 2, 0); BAR; MM(0, aX, b0); BAR;
    // ph6
    RD_A(aX, Ad1, 0, 1); STG_A(t0 + 2, 1); BAR; MM(1, aY, b0); BAR;
    // ph7
    RD_A(aY, Ad1, 1, 1); STG_B(t0 + 3, 0); BAR; MM(0, aX, b1); BAR;
    // ph8: counted wait publishes tile t0+2 (dbuf0); preload its frags
    STG_B(t0 + 3, 1); WAITV(4); BAR; SBAR0;
    RD_A(aX, Ad0, 0, 0); RD_B(b0, Bd0, 0); MM(1, aY, b1); BAR;
  }

  // ---- peeled final iteration (tiles NT-2 in dbuf0, NT-1 in dbuf1) ----
  {
    RD_A(aY, Ad0, 1, 0); RD_B(b1, Bd0, 1); STG_A(NT - 1, 0); BAR; MM(0, aX, b0); BAR;
    RD_A(aX, Ad0, 0, 1); STG_A(NT - 1, 1); BAR; MM(1, aY, b0); BAR;
    RD_A(aY, Ad0, 1, 1); BAR; MM(0, aX, b1); BAR;
    WAITV(0); BAR; SBAR0;
    RD_A(aX, Ad1, 0, 0); RD_B(b0, Bd1, 0); MM(1, aY, b1); BAR;
    RD_A(aY, Ad1, 1, 0); RD_B(b1, Bd1, 1); BAR; MM(0, aX, b0); BAR;
    RD_A(aX, Ad1, 0, 1); BAR; MM(1, aY, b0); BAR;
    RD_A(aY, Ad1, 1, 1); BAR; MM(0, aX, b1); BAR;
    MM(1, aY, b1);
  }

  // ---- epilogue: C/D layout col=lane&15, row=(lane>>4)*4+r [m89-verified] ----
  const int crow0 = bm * BM + wm * 128;
  const int ccol0 = bn * BN + wn * 64;
  const int r0 = (lane >> 4) << 2;
  const int cc = lane & 15;
#pragma unroll
  for (int fi = 0; fi < 8; ++fi)
#pragma unroll
    for (int j = 0; j < 4; ++j) {
      f32x4 v = acc[fi][j];
#pragma unroll
      for (int r = 0; r < 4; ++r)
        C[(int64_t)(crow0 + fi * 16 + r0 + r) * N + (ccol0 + j * 16 + cc)] = v[r];
    }
#undef STG_A
#undef STG_B
#undef RD_A
#undef RD_B
#undef MM
#undef BAR
#undef WAITV
#undef SBAR0
}

// ---------------- fallback (only if ws too small): naive fp32 ---------------
__global__ __launch_bounds__(256) void naive_kernel(
    const float* __restrict__ x, const int* __restrict__ qw,
    const float* __restrict__ sc, float* __restrict__ out)
{
  const int64_t idx = (int64_t)blockIdx.x * 256 + threadIdx.x;
  const int tok = (int)(idx >> 12);
  const int o   = (int)(idx & 4095);
  const float* xr = x + (int64_t)tok * NIN_C;
  const int* qr = qw + (int64_t)o * NIN_C;
  float acc = 0.f;
  for (int g = 0; g < NIN_C / GROUP_C; ++g) {
    float s = sc[(o << 5) | g];
    float ga = 0.f;
#pragma unroll 4
    for (int i = g * GROUP_C; i < (g + 1) * GROUP_C; ++i)
      ga += xr[i] * (float)(qr[i] - QZERO_C);
    acc += s * ga;
  }
  out[idx] = acc;
}

extern "C" void kernel_launch(void* const* d_in, const int* in_sizes, int n_in,
                              void* d_out, int out_size, void* d_ws, size_t ws_size,
                              hipStream_t stream) {
  const float* x  = (const float*)d_in[0];
  const int*   qw = (const int*)d_in[1];
  const float* sc = (const float*)d_in[2];
  float* out = (float*)d_out;

  const size_t xb_bytes = (size_t)TOKENS_C * NIN_C * sizeof(bf16_t);   // 64 MiB
  const size_t wb_bytes = (size_t)NOUT_C * NIN_C * sizeof(bf16_t);     // 32 MiB

  if (ws_size < xb_bytes + wb_bytes) {
    const int64_t total = (int64_t)TOKENS_C * NOUT_C;
    naive_kernel<<<(int)(total / 256), 256, 0, stream>>>(x, qw, sc, out);
    return;
  }

  bf16_t* xb = (bf16_t*)d_ws;
  bf16_t* wb = (bf16_t*)((char*)d_ws + xb_bytes);

  {
    const int64_t elems = (int64_t)TOKENS_C * NIN_C;
    cvt_x_kernel<<<(int)(elems / 8 / 256), 256, 0, stream>>>(x, xb);
  }
  {
    const int64_t elems = (int64_t)NOUT_C * NIN_C;
    dequant_w_kernel<<<(int)(elems / 8 / 256), 256, 0, stream>>>(qw, sc, wb);
  }
  {
    dim3 grid(TOKENS_C / BM, NOUT_C / BN);   // 32 x 16 = 512 wg
    gemm_bt_kernel<<<grid, 512, 0, stream>>>(xb, wb, out);
  }
}

// Round 6
// 264.750 us; speedup vs baseline: 1.0136x; 1.0136x over previous
//
#include <hip/hip_runtime.h>
#include <hip/hip_bf16.h>
#include <stdint.h>

// Problem constants (fixed by reference)
#define TOKENS_C 8192
#define NIN_C    4096
#define NOUT_C   4096
#define GROUP_C  128
#define QZERO_C  8

typedef __bf16 bf16_t;
typedef __bf16  bf16x8 __attribute__((ext_vector_type(8)));
typedef float   f32x4  __attribute__((ext_vector_type(4)));
typedef int     i32x4  __attribute__((ext_vector_type(4)));

#define GAS __attribute__((address_space(1)))
#define LAS __attribute__((address_space(3)))

__device__ __forceinline__ void gload16(const void* g, void* l) {
  __builtin_amdgcn_global_load_lds((const GAS void*)g, (LAS void*)l, 16, 0, 0);
}

// ---------------- pass 1a: dequantize W (int32 codes 0..15) -> bf16 ----------
__global__ __launch_bounds__(256) void dequant_w_kernel(
    const int* __restrict__ qw, const float* __restrict__ sc,
    bf16_t* __restrict__ wb)
{
  const int t = blockIdx.x * 256 + threadIdx.x;
  const int64_t base = (int64_t)t * 8;
  const int o = (int)(base >> 12);
  const int i = (int)(base & 4095);
  const float s = sc[(o << 5) | (i >> 7)];
  i32x4 q0 = *(const i32x4*)(qw + base);
  i32x4 q1 = *(const i32x4*)(qw + base + 4);
  bf16x8 r;
  r[0] = (bf16_t)((float)(q0[0] - QZERO_C) * s);
  r[1] = (bf16_t)((float)(q0[1] - QZERO_C) * s);
  r[2] = (bf16_t)((float)(q0[2] - QZERO_C) * s);
  r[3] = (bf16_t)((float)(q0[3] - QZERO_C) * s);
  r[4] = (bf16_t)((float)(q1[0] - QZERO_C) * s);
  r[5] = (bf16_t)((float)(q1[1] - QZERO_C) * s);
  r[6] = (bf16_t)((float)(q1[2] - QZERO_C) * s);
  r[7] = (bf16_t)((float)(q1[3] - QZERO_C) * s);
  *(bf16x8*)(wb + base) = r;
}

// ---------------- pass 1b: convert x fp32 -> bf16 ----------------------------
__global__ __launch_bounds__(256) void cvt_x_kernel(
    const float* __restrict__ x, bf16_t* __restrict__ xb)
{
  const int t = blockIdx.x * 256 + threadIdx.x;
  const int64_t base = (int64_t)t * 8;
  f32x4 a = *(const f32x4*)(x + base);
  f32x4 b = *(const f32x4*)(x + base + 4);
  bf16x8 r;
  r[0] = (bf16_t)a[0]; r[1] = (bf16_t)a[1]; r[2] = (bf16_t)a[2]; r[3] = (bf16_t)a[3];
  r[4] = (bf16_t)b[0]; r[5] = (bf16_t)b[1]; r[6] = (bf16_t)b[2]; r[7] = (bf16_t)b[3];
  *(bf16x8*)(xb + base) = r;
}

// ---------------- pass 2: bf16 GEMM, C[M,N] = A[M,K] * B[N,K]^T --------------
// R4 8-phase schedule with ONE barrier per phase (pre-MM barrier removed).
// Safety invariant: each phase's ds_reads complete before its MM finishes
// (in-order lgkm + consumed-read issued last), so one post-MM barrier
// separates all readers from all later-phase LDS writers. Counted vmcnt(4)
// at phases 4/8 (after MM), never 0 in main loop.
#define BM 256
#define BN 256
#define BK 64
#define NT (NIN_C / BK)   // 64 K-tiles -> 32 iterations of 2

__global__ __launch_bounds__(512, 2) void gemm_bt_kernel(
    const bf16_t* __restrict__ A,   // [M][K] bf16 (x)
    const bf16_t* __restrict__ B,   // [N][K] bf16 (W)
    float* __restrict__ C)          // [M][N] f32
{
  constexpr int K = NIN_C, N = NOUT_C;
  constexpr int K2 = K * 2;
  // A: dbuf d, half h at smem + d*32768 + h*16384
  // B: dbuf d, half h at smem + 65536 + d*32768 + h*16384
  __shared__ char smem[131072];

  const int tid  = threadIdx.x;
  const int lane = tid & 63;
  const int wid  = tid >> 6;       // 0..7
  const int wm   = wid >> 2;       // 0..1  -> 128 rows of C (== A half index)
  const int wn   = wid & 3;        // 0..3  -> 64 cols of C (B half = wn>>1)
  const int bm   = blockIdx.x;
  const int bn   = blockIdx.y;

  // ---- staging geometry: half = 128 rows x 128B; thread covers slots wid*2+l
  // (each 8 rows x 128B = 1KB); lane -> row slot*8+(lane>>3), granule lane&7.
  // LDS dest LINEAR; global source granule pre-swizzled with involution
  // g ^= (row&7) == (lane>>3). [R2/R4-verified: 0 bank conflicts]
  const int cswz = (((lane & 7) ^ (lane >> 3)) << 4);
  const char* Ag = (const char*)A;
  const char* Bg = (const char*)B;
  int64_t aso[2][2], bso[2][2];    // [half][l]
#pragma unroll
  for (int h = 0; h < 2; ++h)
#pragma unroll
    for (int l = 0; l < 2; ++l) {
      const int r = h * 128 + (wid * 2 + l) * 8 + (lane >> 3);
      aso[h][l] = (int64_t)(bm * BM + r) * K2 + cswz;
      bso[h][l] = (int64_t)(bn * BN + r) * K2 + cswz;
    }
  const int sdst = wid * 2048 + (lane << 4);  // + 1024 for l=1

#define STG_A(tt, h) { char* d_ = smem + (((tt) & 1) << 15) + ((h) << 14) + sdst; \
    gload16(Ag + aso[h][0] + (int64_t)(tt) * 128, d_);                            \
    gload16(Ag + aso[h][1] + (int64_t)(tt) * 128, d_ + 1024); }
#define STG_B(tt, h) { char* d_ = smem + 65536 + (((tt) & 1) << 15) + ((h) << 14) + sdst; \
    gload16(Bg + bso[h][0] + (int64_t)(tt) * 128, d_);                            \
    gload16(Bg + bso[h][1] + (int64_t)(tt) * 128, d_ + 1024); }

  // ---- fragment read geometry (16x16x32, BK=64 -> 2 k-subs) ----
  const int frow  = lane & 15;
  const int fcol0 = (((lane >> 4) ^ (lane & 7)) << 4);  // ks adds ^(ks<<6)

  // NOTE: within each phase, reads consumed by this phase's MM are issued
  // LAST (RD_B before RD_A) so in-order lgkm completion covers all of them.
#define RD_B(dst, BB, ks)                                                      \
  _Pragma("unroll")                                                            \
  for (int j = 0; j < 4; ++j)                                                  \
    dst[j] = *(const bf16x8*)((BB) + ((wn & 1) * 64 + j * 16 + frow) * 128 +   \
                              (fcol0 ^ ((ks) << 6)));
#define RD_A(AB, mh, ks)                                                       \
  _Pragma("unroll")                                                            \
  for (int i = 0; i < 4; ++i)                                                  \
    a[i] = *(const bf16x8*)((AB) + ((mh) * 64 + i * 16 + frow) * 128 +         \
                            (fcol0 ^ ((ks) << 6)));
#define MM(mh, bv)                                                             \
  __builtin_amdgcn_s_setprio(1);                                               \
  _Pragma("unroll")                                                            \
  for (int i = 0; i < 4; ++i)                                                  \
    _Pragma("unroll")                                                          \
    for (int j = 0; j < 4; ++j)                                                \
      acc[(mh) * 4 + i][j] = __builtin_amdgcn_mfma_f32_16x16x32_bf16(          \
          a[i], bv[j], acc[(mh) * 4 + i][j], 0, 0, 0);                         \
  __builtin_amdgcn_s_setprio(0);
#define BAR __builtin_amdgcn_s_barrier()
#define WAITV(n) asm volatile("s_waitcnt vmcnt(" #n ")" ::: "memory")
#define SBAR0 __builtin_amdgcn_sched_barrier(0)

  const char* Ad0 = smem + wm * 16384;
  const char* Ad1 = smem + 32768 + wm * 16384;
  const char* Bd0 = smem + 65536 + (wn >> 1) * 16384;
  const char* Bd1 = smem + 98304 + (wn >> 1) * 16384;

  f32x4 acc[8][4] = {};
  bf16x8 a[4], b0[4], b1[4];

  // ---- prologue: stage tile0 A+B, tile1 B; force tile0 landed ----
  STG_A(0, 0); STG_A(0, 1);
  STG_B(0, 0); STG_B(0, 1);
  STG_B(1, 0); STG_B(1, 1);
  WAITV(4);                 // 12 issued; oldest 8 (tile0) done, B(1) in flight
  BAR; SBAR0;

  // ---- main loop: iteration i computes tiles 2i (dbuf0), 2i+1 (dbuf1);
  // stages A(2i+1)@ph1/2, B(2i+2)@ph3/4, A(2i+2)@ph5/6, B(2i+3)@ph7/8.
  // ONE barrier per phase (post-MM); WAITV after MM at ph4/ph8.
  for (int i = 0; i < NT / 2 - 1; ++i) {
    const int t0 = 2 * i;
    // ph1
    RD_B(b0, Bd0, 0); RD_A(Ad0, 0, 0); STG_A(t0 + 1, 0); MM(0, b0); BAR;
    // ph2
    RD_B(b1, Bd0, 1); RD_A(Ad0, 1, 0); STG_A(t0 + 1, 1); MM(1, b0); BAR;
    // ph3
    RD_A(Ad0, 0, 1); STG_B(t0 + 2, 0); MM(0, b1); BAR;
    // ph4: counted wait after MM; BAR publishes dbuf1 (tile t0+1)
    RD_A(Ad0, 1, 1); STG_B(t0 + 2, 1); MM(1, b1); WAITV(4); BAR; SBAR0;
    // ph5
    RD_B(b0, Bd1, 0); RD_A(Ad1, 0, 0); STG_A(t0 + 2, 0); MM(0, b0); BAR;
    // ph6
    RD_B(b1, Bd1, 1); RD_A(Ad1, 1, 0); STG_A(t0 + 2, 1); MM(1, b0); BAR;
    // ph7
    RD_A(Ad1, 0, 1); STG_B(t0 + 3, 0); MM(0, b1); BAR;
    // ph8: counted wait after MM; BAR publishes dbuf0 (tile t0+2)
    RD_A(Ad1, 1, 1); STG_B(t0 + 3, 1); MM(1, b1); WAITV(4); BAR; SBAR0;
  }

  // ---- peeled final iteration (tiles NT-2 in dbuf0, NT-1 in dbuf1) ----
  {
    RD_B(b0, Bd0, 0); RD_A(Ad0, 0, 0); STG_A(NT - 1, 0); MM(0, b0); BAR;
    RD_B(b1, Bd0, 1); RD_A(Ad0, 1, 0); STG_A(NT - 1, 1); MM(1, b0); BAR;
    RD_A(Ad0, 0, 1); MM(0, b1); BAR;
    RD_A(Ad0, 1, 1); MM(1, b1); WAITV(0); BAR; SBAR0;
    RD_B(b0, Bd1, 0); RD_A(Ad1, 0, 0); MM(0, b0); BAR;
    RD_B(b1, Bd1, 1); RD_A(Ad1, 1, 0); MM(1, b0); BAR;
    RD_A(Ad1, 0, 1); MM(0, b1); BAR;
    RD_A(Ad1, 1, 1); MM(1, b1);
  }

  // ---- epilogue: C/D layout col=lane&15, row=(lane>>4)*4+r [m89-verified] ----
  const int crow0 = bm * BM + wm * 128;
  const int ccol0 = bn * BN + wn * 64;
  const int r0 = (lane >> 4) << 2;
  const int cc = lane & 15;
#pragma unroll
  for (int fi = 0; fi < 8; ++fi)
#pragma unroll
    for (int j = 0; j < 4; ++j) {
      f32x4 v = acc[fi][j];
#pragma unroll
      for (int r = 0; r < 4; ++r)
        C[(int64_t)(crow0 + fi * 16 + r0 + r) * N + (ccol0 + j * 16 + cc)] = v[r];
    }
#undef STG_A
#undef STG_B
#undef RD_A
#undef RD_B
#undef MM
#undef BAR
#undef WAITV
#undef SBAR0
}

// ---------------- fallback (only if ws too small): naive fp32 ---------------
__global__ __launch_bounds__(256) void naive_kernel(
    const float* __restrict__ x, const int* __restrict__ qw,
    const float* __restrict__ sc, float* __restrict__ out)
{
  const int64_t idx = (int64_t)blockIdx.x * 256 + threadIdx.x;
  const int tok = (int)(idx >> 12);
  const int o   = (int)(idx & 4095);
  const float* xr = x + (int64_t)tok * NIN_C;
  const int* qr = qw + (int64_t)o * NIN_C;
  float acc = 0.f;
  for (int g = 0; g < NIN_C / GROUP_C; ++g) {
    float s = sc[(o << 5) | g];
    float ga = 0.f;
#pragma unroll 4
    for (int i = g * GROUP_C; i < (g + 1) * GROUP_C; ++i)
      ga += xr[i] * (float)(qr[i] - QZERO_C);
    acc += s * ga;
  }
  out[idx] = acc;
}

extern "C" void kernel_launch(void* const* d_in, const int* in_sizes, int n_in,
                              void* d_out, int out_size, void* d_ws, size_t ws_size,
                              hipStream_t stream) {
  const float* x  = (const float*)d_in[0];
  const int*   qw = (const int*)d_in[1];
  const float* sc = (const float*)d_in[2];
  float* out = (float*)d_out;

  const size_t xb_bytes = (size_t)TOKENS_C * NIN_C * sizeof(bf16_t);   // 64 MiB
  const size_t wb_bytes = (size_t)NOUT_C * NIN_C * sizeof(bf16_t);     // 32 MiB

  if (ws_size < xb_bytes + wb_bytes) {
    const int64_t total = (int64_t)TOKENS_C * NOUT_C;
    naive_kernel<<<(int)(total / 256), 256, 0, stream>>>(x, qw, sc, out);
    return;
  }

  bf16_t* xb = (bf16_t*)d_ws;
  bf16_t* wb = (bf16_t*)((char*)d_ws + xb_bytes);

  {
    const int64_t elems = (int64_t)TOKENS_C * NIN_C;
    cvt_x_kernel<<<(int)(elems / 8 / 256), 256, 0, stream>>>(x, xb);
  }
  {
    const int64_t elems = (int64_t)NOUT_C * NIN_C;
    dequant_w_kernel<<<(int)(elems / 8 / 256), 256, 0, stream>>>(qw, sc, wb);
  }
  {
    dim3 grid(TOKENS_C / BM, NOUT_C / BN);   // 32 x 16 = 512 wg
    gemm_bt_kernel<<<grid, 512, 0, stream>>>(xb, wb, out);
  }
}